// Round 5
// baseline (191.415 us; speedup 1.0000x reference)
//
#include <hip/hip_runtime.h>
#include <hip/hip_bf16.h>

static constexpr int NN  = 50000;  // nodes
static constexpr int KNB = 32;     // neighbors
static constexpr int F   = 128;    // features
static constexpr int E   = 8;      // edge features
static constexpr int TI  = 16;     // nodes per block (3125 blocks)
static constexpr int LN  = F * E;  // 1024 contraction length

typedef __attribute__((ext_vector_type(8))) short short8v;
typedef __attribute__((ext_vector_type(4))) float f32x4;

__device__ __forceinline__ unsigned short f2bf(float x) {
    unsigned u = __float_as_uint(x);
    unsigned r = (u + 0x7fff + ((u >> 16) & 1)) >> 16;   // RNE
    return (unsigned short)r;
}
__device__ __forceinline__ float bf2f(unsigned short b) {
    return __uint_as_float(((unsigned)b) << 16);
}

// async global->LDS, 4B per lane: LDS dest = uniform base + lane*4 (HW),
// global src = per-lane address. Fire-and-forget, tracked by vmcnt.
__device__ __forceinline__ void gload_lds4(const unsigned* gsrc, unsigned short* ldst) {
    __builtin_amdgcn_global_load_lds(
        (const __attribute__((address_space(1))) unsigned*)gsrc,
        (__attribute__((address_space(3))) unsigned*)ldst, 4, 0, 0);
}

// ---------- prep A: w[l,m,n] -> W2f bf16 in B-fragment order ----------
// W2f[((kb*128 + m)*4 + kq)*8 + e8] = bf16( w[l,m,n] ) where
//   k = kb*32 + kq*4 + (e8&3) + (e8>>2)*16 ,  l = k>>3, n = k&7
__global__ void prep_w_kernel(const float* __restrict__ w, unsigned short* __restrict__ w2f) {
    int o  = blockIdx.x * 256 + threadIdx.x;          // 131072 total
    int e8 = o & 7, kq = (o >> 3) & 3, m = (o >> 5) & 127, kb = o >> 12;
    int k  = kb * 32 + kq * 4 + (e8 & 3) + ((e8 >> 2) << 4);
    int l  = k >> 3, n = k & 7;
    w2f[o] = f2bf(w[(size_t)(l * F + m) * E + n]);
}

// ---------- prep B: nodes fp32 -> bf16 (3125 blocks x 256 thr x 8 elems = exact) ----------
__global__ void prep_nodes_kernel(const float* __restrict__ nodes, unsigned short* __restrict__ nb) {
    int t = blockIdx.x * 256 + threadIdx.x;
    const float4* s = (const float4*)nodes + (size_t)t * 2;
    float4 a = s[0], b = s[1];
    uint4 pk;
    pk.x = (unsigned)f2bf(a.x) | ((unsigned)f2bf(a.y) << 16);
    pk.y = (unsigned)f2bf(a.z) | ((unsigned)f2bf(a.w) << 16);
    pk.z = (unsigned)f2bf(b.x) | ((unsigned)f2bf(b.y) << 16);
    pk.w = (unsigned)f2bf(b.z) | ((unsigned)f2bf(b.w) << 16);
    ((uint4*)nb)[t] = pk;
}

// ---------- main fused kernel ----------
// stage 1: T[ii][ln] = sum_j edges[i,j,n]*nodes[nlist[i,j],l]  (bf16 in LDS, swizzled)
//   Gathers staged via global_load_lds into per-wave LDS buffers (no VGPR cost),
//   16-row chunks, double-buffered, counted vmcnt(16) so next chunk stays in flight.
// stage 2: MFMA out[i][m] = inv[i] * sum_ln T[ii][ln] * W2[ln][m]
template<bool NB>
__global__ __launch_bounds__(256, 2)
void mp_main_kernel(const float* __restrict__ nodes,
                    const unsigned short* __restrict__ nodesBf,
                    const int*   __restrict__ nlist,
                    const float* __restrict__ edges,
                    const float* __restrict__ inv_degree,
                    const unsigned short* __restrict__ w2f,
                    float* __restrict__ out)
{
    __shared__ unsigned short tS[TI * LN];            // 32 KiB T (swizzled)
    __shared__ unsigned short stg[4][2][16 * F];      // 32 KiB staging: 4 waves x 2 bufs x 4KB
    const int tid    = threadIdx.x;
    const int wv     = __builtin_amdgcn_readfirstlane(tid >> 6);   // wave id 0..3
    const int lane   = tid & 63;
    const int i_base = blockIdx.x * TI;
    char* tB = (char*)tS;

    if (NB) {
        // ---------------- stage 1: 4 nodes/wave, 8 chunks of 16 rows ----------------
        float a0[E], a1[E];
        #pragma unroll
        for (int n = 0; n < E; ++n) { a0[n] = 0.f; a1[n] = 0.f; }

        // issue chunk 0
        {
            const int gi = i_base + wv * 4;
            const int* nl = nlist + (size_t)gi * KNB;
            unsigned short* dst = &stg[wv][0][0];
            #pragma unroll
            for (int j = 0; j < 16; ++j) {
                unsigned idx = (unsigned)nl[j];
                if (idx >= (unsigned)NN) idx = 0u;
                gload_lds4((const unsigned*)(nodesBf + (size_t)idx * F) + lane, dst + j * F);
            }
        }

        #pragma unroll
        for (int c = 0; c < 8; ++c) {
            const int node = c >> 1, half = c & 1;
            // issue chunk c+1 (opposite buffer) BEFORE waiting on chunk c
            if (c < 7) {
                const int c1 = c + 1;
                const int gi1 = i_base + wv * 4 + (c1 >> 1);
                const int* nl1 = nlist + (size_t)gi1 * KNB + (c1 & 1) * 16;
                unsigned short* dst = &stg[wv][c1 & 1][0];
                #pragma unroll
                for (int j = 0; j < 16; ++j) {
                    unsigned idx = (unsigned)nl1[j];
                    if (idx >= (unsigned)NN) idx = 0u;
                    gload_lds4((const unsigned*)(nodesBf + (size_t)idx * F) + lane, dst + j * F);
                }
                // wait: oldest 16 (chunk c) landed; chunk c+1's 16 stay in flight
                asm volatile("s_waitcnt vmcnt(16)" ::: "memory");
            } else {
                asm volatile("s_waitcnt vmcnt(0)" ::: "memory");
            }

            // consume chunk c: 16 rows from LDS, FMA with uniform edge coeffs
            const int gi = i_base + wv * 4 + node;
            const float* ep = edges + ((size_t)gi * KNB + half * 16) * E;
            const unsigned short* sb = &stg[wv][half][0];
            #pragma unroll
            for (int j = 0; j < 16; ++j) {
                const unsigned pv = *(const unsigned*)(sb + j * F + lane * 2);
                const float v0 = bf2f((unsigned short)(pv & 0xffff));
                const float v1 = bf2f((unsigned short)(pv >> 16));
                const float4 e0 = *(const float4*)(ep + j * 8);      // uniform -> s_load
                const float4 e1 = *(const float4*)(ep + j * 8 + 4);
                a0[0] = __builtin_fmaf(e0.x, v0, a0[0]); a1[0] = __builtin_fmaf(e0.x, v1, a1[0]);
                a0[1] = __builtin_fmaf(e0.y, v0, a0[1]); a1[1] = __builtin_fmaf(e0.y, v1, a1[1]);
                a0[2] = __builtin_fmaf(e0.z, v0, a0[2]); a1[2] = __builtin_fmaf(e0.z, v1, a1[2]);
                a0[3] = __builtin_fmaf(e0.w, v0, a0[3]); a1[3] = __builtin_fmaf(e0.w, v1, a1[3]);
                a0[4] = __builtin_fmaf(e1.x, v0, a0[4]); a1[4] = __builtin_fmaf(e1.x, v1, a1[4]);
                a0[5] = __builtin_fmaf(e1.y, v0, a0[5]); a1[5] = __builtin_fmaf(e1.y, v1, a1[5]);
                a0[6] = __builtin_fmaf(e1.z, v0, a0[6]); a1[6] = __builtin_fmaf(e1.z, v1, a1[6]);
                a0[7] = __builtin_fmaf(e1.w, v0, a0[7]); a1[7] = __builtin_fmaf(e1.w, v1, a1[7]);
            }

            if (half == 1) {
                // finalize node: pack bf16, swizzled T store (layout as R2-R4)
                const int row = wv * 4 + node;
                uint4 pk0, pk1;
                pk0.x = (unsigned)f2bf(a0[0]) | ((unsigned)f2bf(a0[1]) << 16);
                pk0.y = (unsigned)f2bf(a0[2]) | ((unsigned)f2bf(a0[3]) << 16);
                pk0.z = (unsigned)f2bf(a0[4]) | ((unsigned)f2bf(a0[5]) << 16);
                pk0.w = (unsigned)f2bf(a0[6]) | ((unsigned)f2bf(a0[7]) << 16);
                pk1.x = (unsigned)f2bf(a1[0]) | ((unsigned)f2bf(a1[1]) << 16);
                pk1.y = (unsigned)f2bf(a1[2]) | ((unsigned)f2bf(a1[3]) << 16);
                pk1.z = (unsigned)f2bf(a1[4]) | ((unsigned)f2bf(a1[5]) << 16);
                pk1.w = (unsigned)f2bf(a1[6]) | ((unsigned)f2bf(a1[7]) << 16);
                const int p2 = (lane >> 2) & 1;
                const int s  = (row & 7) << 4;
                const int rb = row * (LN * 2);
                const uint4 first  = p2 ? pk1 : pk0;
                const uint4 second = p2 ? pk0 : pk1;
                *(uint4*)(tB + rb + ((lane * 32 + (p2 << 4))      ^ s)) = first;
                *(uint4*)(tB + rb + ((lane * 32 + 16 - (p2 << 4)) ^ s)) = second;
                #pragma unroll
                for (int n = 0; n < E; ++n) { a0[n] = 0.f; a1[n] = 0.f; }
            }
        }
    } else {
        // fallback: direct fp32 gathers (rarely used)
        for (int it = 0; it < 4; ++it) {
            const int row = wv * 4 + it;
            const int i   = i_base + row;
            const int*   nl = nlist + (size_t)i * KNB;
            const float* ep = edges + (size_t)i * (KNB * E);
            float a0[E], a1[E];
            #pragma unroll
            for (int n = 0; n < E; ++n) { a0[n] = 0.f; a1[n] = 0.f; }
            #pragma unroll 4
            for (int j = 0; j < KNB; ++j) {
                unsigned idx = (unsigned)nl[j];
                if (idx >= (unsigned)NN) idx = 0u;
                const float2 fv = ((const float2*)(nodes + (size_t)idx * F))[lane];
                const float4 e0 = *(const float4*)(ep + j * 8);
                const float4 e1 = *(const float4*)(ep + j * 8 + 4);
                a0[0] = __builtin_fmaf(e0.x, fv.x, a0[0]); a1[0] = __builtin_fmaf(e0.x, fv.y, a1[0]);
                a0[1] = __builtin_fmaf(e0.y, fv.x, a0[1]); a1[1] = __builtin_fmaf(e0.y, fv.y, a1[1]);
                a0[2] = __builtin_fmaf(e0.z, fv.x, a0[2]); a1[2] = __builtin_fmaf(e0.z, fv.y, a1[2]);
                a0[3] = __builtin_fmaf(e0.w, fv.x, a0[3]); a1[3] = __builtin_fmaf(e0.w, fv.y, a1[3]);
                a0[4] = __builtin_fmaf(e1.x, fv.x, a0[4]); a1[4] = __builtin_fmaf(e1.x, fv.y, a1[4]);
                a0[5] = __builtin_fmaf(e1.y, fv.x, a0[5]); a1[5] = __builtin_fmaf(e1.y, fv.y, a1[5]);
                a0[6] = __builtin_fmaf(e1.z, fv.x, a0[6]); a1[6] = __builtin_fmaf(e1.z, fv.y, a1[6]);
                a0[7] = __builtin_fmaf(e1.w, fv.x, a0[7]); a1[7] = __builtin_fmaf(e1.w, fv.y, a1[7]);
            }
            uint4 pk0, pk1;
            pk0.x = (unsigned)f2bf(a0[0]) | ((unsigned)f2bf(a0[1]) << 16);
            pk0.y = (unsigned)f2bf(a0[2]) | ((unsigned)f2bf(a0[3]) << 16);
            pk0.z = (unsigned)f2bf(a0[4]) | ((unsigned)f2bf(a0[5]) << 16);
            pk0.w = (unsigned)f2bf(a0[6]) | ((unsigned)f2bf(a0[7]) << 16);
            pk1.x = (unsigned)f2bf(a1[0]) | ((unsigned)f2bf(a1[1]) << 16);
            pk1.y = (unsigned)f2bf(a1[2]) | ((unsigned)f2bf(a1[3]) << 16);
            pk1.z = (unsigned)f2bf(a1[4]) | ((unsigned)f2bf(a1[5]) << 16);
            pk1.w = (unsigned)f2bf(a1[6]) | ((unsigned)f2bf(a1[7]) << 16);
            const int s  = (row & 7) << 4;
            const int rb = row * (LN * 2);
            *(uint4*)(tB + rb + ((lane * 32)      ^ s)) = pk0;
            *(uint4*)(tB + rb + ((lane * 32 + 16) ^ s)) = pk1;
        }
    }
    __syncthreads();

    // ---------------- stage 2: MFMA ----------------
    const int colm = lane & 15;                       // i-row for A, m-col for B/C
    const int kq   = lane >> 4;
    const int mt0  = wv * 2, mt1 = wv * 2 + 1;

    f32x4 c0 = {0.f, 0.f, 0.f, 0.f};
    f32x4 c1 = {0.f, 0.f, 0.f, 0.f};

    const int arow = colm * (LN * 2);
    const int asw  = (colm & 7) << 4;

    #pragma unroll 4
    for (int kb = 0; kb < LN / 32; ++kb) {
        union { short8v v; uint2 u[2]; } af;
        af.u[0] = *(const uint2*)(tB + arow + ((kb * 64      + kq * 8) ^ asw)); // k=kb*32+kq*4+e
        af.u[1] = *(const uint2*)(tB + arow + ((kb * 64 + 32 + kq * 8) ^ asw)); // k=kb*32+16+kq*4+e
        union { short8v v; uint4 u; } b0, b1;
        b0.u = *(const uint4*)(w2f + ((size_t)((kb * 128 + mt0 * 16 + colm) * 4 + kq)) * 8);
        b1.u = *(const uint4*)(w2f + ((size_t)((kb * 128 + mt1 * 16 + colm) * 4 + kq)) * 8);
        c0 = __builtin_amdgcn_mfma_f32_16x16x32_bf16(af.v, b0.v, c0, 0, 0, 0);
        c1 = __builtin_amdgcn_mfma_f32_16x16x32_bf16(af.v, b1.v, c1, 0, 0, 0);
    }

    // C/D: col = lane&15, row = (lane>>4)*4 + r   [measured m89]
    #pragma unroll
    for (int r = 0; r < 4; ++r) {
        const int ii = kq * 4 + r;
        const int gi = i_base + ii;
        const float sc = inv_degree[gi];
        out[(size_t)gi * F + mt0 * 16 + colm] = sc * c0[r];
        out[(size_t)gi * F + mt1 * 16 + colm] = sc * c1[r];
    }
}

// ---------- fallback (round-1 kernel, pure fp32) for tiny ws ----------
__global__ __launch_bounds__(256, 2)
void mp_fused_fallback(const float* __restrict__ nodes, const int* __restrict__ nlist,
                       const float* __restrict__ edges, const float* __restrict__ inv_degree,
                       const float* __restrict__ w, float* __restrict__ out)
{
    __shared__ float tLds[TI * F * E];
    const int tid = threadIdx.x;
    const int i_base = blockIdx.x * TI;
    {
        const int l = tid & (F - 1);
        const int half = __builtin_amdgcn_readfirstlane(tid >> 7);
        for (int g = 0; g < TI / 2; ++g) {
            const int ii = g * 2 + half;
            const int i = i_base + ii;
            float acc[E];
            #pragma unroll
            for (int n = 0; n < E; ++n) acc[n] = 0.f;
            const int* nl = nlist + i * KNB;
            const float* ep = edges + (size_t)i * (KNB * E);
            #pragma unroll 4
            for (int j = 0; j < KNB; ++j) {
                unsigned idx = (unsigned)nl[j];
                if (idx >= (unsigned)NN) idx = 0u;
                const float v = nodes[idx * F + l];
                #pragma unroll
                for (int n = 0; n < E; ++n) acc[n] = __builtin_fmaf(ep[j * E + n], v, acc[n]);
            }
            float4* dst = (float4*)&tLds[ii * (F * E) + l * E];
            dst[0] = make_float4(acc[0], acc[1], acc[2], acc[3]);
            dst[1] = make_float4(acc[4], acc[5], acc[6], acc[7]);
        }
    }
    __syncthreads();
    const int m_lo = tid & 63;
    const int q = __builtin_amdgcn_readfirstlane(tid >> 6);
    float accA[TI], accB[TI];
    #pragma unroll
    for (int ii = 0; ii < TI; ++ii) { accA[ii] = 0.f; accB[ii] = 0.f; }
    for (int lq = 0; lq < F / 4; ++lq) {
        const int l = q * (F / 4) + lq;
        const float4* wp0 = (const float4*)&w[(size_t)l * (F * E) + (size_t)m_lo * E];
        const float4* wp1 = (const float4*)&w[(size_t)l * (F * E) + (size_t)(m_lo + 64) * E];
        const float4 w0a = wp0[0], w0b = wp0[1];
        const float4 w1a = wp1[0], w1b = wp1[1];
        #pragma unroll
        for (int ii = 0; ii < TI; ++ii) {
            const float4* tp = (const float4*)&tLds[ii * (F * E) + l * E];
            const float4 ta = tp[0], tb = tp[1];
            float sA = accA[ii], sB = accB[ii];
            sA = __builtin_fmaf(ta.x, w0a.x, sA); sA = __builtin_fmaf(ta.y, w0a.y, sA);
            sA = __builtin_fmaf(ta.z, w0a.z, sA); sA = __builtin_fmaf(ta.w, w0a.w, sA);
            sA = __builtin_fmaf(tb.x, w0b.x, sA); sA = __builtin_fmaf(tb.y, w0b.y, sA);
            sA = __builtin_fmaf(tb.z, w0b.z, sA); sA = __builtin_fmaf(tb.w, w0b.w, sA);
            sB = __builtin_fmaf(ta.x, w1a.x, sB); sB = __builtin_fmaf(ta.y, w1a.y, sB);
            sB = __builtin_fmaf(ta.z, w1a.z, sB); sB = __builtin_fmaf(ta.w, w1a.w, sB);
            sB = __builtin_fmaf(tb.x, w1b.x, sB); sB = __builtin_fmaf(tb.y, w1b.y, sB);
            sB = __builtin_fmaf(tb.z, w1b.z, sB); sB = __builtin_fmaf(tb.w, w1b.w, sB);
            accA[ii] = sA; accB[ii] = sB;
        }
    }
    __syncthreads();
    float* pLds = tLds;
    #pragma unroll
    for (int ii = 0; ii < TI; ++ii) {
        pLds[q * (TI * F) + ii * F + m_lo] = accA[ii];
        pLds[q * (TI * F) + ii * F + m_lo + 64] = accB[ii];
    }
    __syncthreads();
    #pragma unroll
    for (int r = 0; r < (TI * F) / 256; ++r) {
        const int o = r * 256 + tid;
        const int ii = o >> 7;
        const int m = o & (F - 1);
        const float s = pLds[0 * (TI * F) + ii * F + m] + pLds[1 * (TI * F) + ii * F + m]
                      + pLds[2 * (TI * F) + ii * F + m] + pLds[3 * (TI * F) + ii * F + m];
        const int i = i_base + ii;
        out[(size_t)i * F + m] = inv_degree[i] * s;
    }
}

extern "C" void kernel_launch(void* const* d_in, const int* in_sizes, int n_in,
                              void* d_out, int out_size, void* d_ws, size_t ws_size,
                              hipStream_t stream) {
    const float* nodes      = (const float*)d_in[0];
    const int*   nlist      = (const int*)d_in[1];
    const float* edges      = (const float*)d_in[2];
    const float* inv_degree = (const float*)d_in[3];
    const float* w          = (const float*)d_in[4];
    float* out = (float*)d_out;
    (void)in_sizes; (void)n_in; (void)out_size;

    const size_t need_w2 = (size_t)LN * F * 2;                  // 256 KiB
    const size_t need_nb = (size_t)NN * F * 2;                  // 12.8 MiB

    if (ws_size < need_w2) {
        mp_fused_fallback<<<dim3(NN / TI), dim3(256), 0, stream>>>(
            nodes, nlist, edges, inv_degree, w, out);
        return;
    }
    unsigned short* w2f = (unsigned short*)d_ws;
    unsigned short* nb  = (unsigned short*)((char*)d_ws + need_w2);

    prep_w_kernel<<<dim3((LN * F) / 256), dim3(256), 0, stream>>>(w, w2f);
    if (ws_size >= need_w2 + need_nb) {
        prep_nodes_kernel<<<dim3(NN * F / 8 / 256), dim3(256), 0, stream>>>(nodes, nb);
        mp_main_kernel<true><<<dim3(NN / TI), dim3(256), 0, stream>>>(
            nodes, nb, nlist, edges, inv_degree, w2f, out);
    } else {
        mp_main_kernel<false><<<dim3(NN / TI), dim3(256), 0, stream>>>(
            nodes, nb, nlist, edges, inv_degree, w2f, out);
    }
}

// Round 6
// 120.007 us; speedup vs baseline: 1.5950x; 1.5950x over previous
//
#include <hip/hip_runtime.h>
#include <hip/hip_bf16.h>

static constexpr int NN  = 50000;  // nodes
static constexpr int KNB = 32;     // neighbors
static constexpr int F   = 128;    // features
static constexpr int E   = 8;      // edge features
static constexpr int TI  = 16;     // nodes per block (3125 blocks)
static constexpr int LN  = F * E;  // 1024 contraction length

typedef __attribute__((ext_vector_type(8))) short short8v;
typedef __attribute__((ext_vector_type(4))) float f32x4;

__device__ __forceinline__ unsigned short f2bf(float x) {
    unsigned u = __float_as_uint(x);
    unsigned r = (u + 0x7fff + ((u >> 16) & 1)) >> 16;   // RNE
    return (unsigned short)r;
}
__device__ __forceinline__ float bf2f(unsigned short b) {
    return __uint_as_float(((unsigned)b) << 16);
}

// ---------- prep A: w[l,m,n] -> W2f bf16 in B-fragment order ----------
// W2f[((kb*128 + m)*4 + kq)*8 + e8] = bf16( w[l,m,n] ) where
//   k = kb*32 + kq*4 + (e8&3) + (e8>>2)*16 ,  l = k>>3, n = k&7
__global__ void prep_w_kernel(const float* __restrict__ w, unsigned short* __restrict__ w2f) {
    int o  = blockIdx.x * 256 + threadIdx.x;          // 131072 total
    int e8 = o & 7, kq = (o >> 3) & 3, m = (o >> 5) & 127, kb = o >> 12;
    int k  = kb * 32 + kq * 4 + (e8 & 3) + ((e8 >> 2) << 4);
    int l  = k >> 3, n = k & 7;
    w2f[o] = f2bf(w[(size_t)(l * F + m) * E + n]);
}

// ---------- prep B: nodes fp32 -> bf16 (3125 blocks x 256 thr x 8 elems = exact) ----------
__global__ void prep_nodes_kernel(const float* __restrict__ nodes, unsigned short* __restrict__ nb) {
    int t = blockIdx.x * 256 + threadIdx.x;
    const float4* s = (const float4*)nodes + (size_t)t * 2;
    float4 a = s[0], b = s[1];
    uint4 pk;
    pk.x = (unsigned)f2bf(a.x) | ((unsigned)f2bf(a.y) << 16);
    pk.y = (unsigned)f2bf(a.z) | ((unsigned)f2bf(a.w) << 16);
    pk.z = (unsigned)f2bf(b.x) | ((unsigned)f2bf(b.y) << 16);
    pk.w = (unsigned)f2bf(b.z) | ((unsigned)f2bf(b.w) << 16);
    ((uint4*)nb)[t] = pk;
}

// ---------- main fused kernel ----------
// stage 1 (VALU): per row, BATCH-ISSUE all 32 gathers into registers, then a
//   sched_barrier(0) fence (scheduler cannot sink loads past it -> 32 loads in
//   flight per wave), then consume in issue order (rolling vmcnt waits).
// stage 2 (MFMA): out[i][m] = inv[i] * sum_ln T[ii][ln] * W2[ln][m]
template<bool NB>
__global__ __launch_bounds__(256, 4)
void mp_main_kernel(const float* __restrict__ nodes,
                    const unsigned short* __restrict__ nodesBf,
                    const int*   __restrict__ nlist,
                    const float* __restrict__ edges,
                    const float* __restrict__ inv_degree,
                    const unsigned short* __restrict__ w2f,
                    float* __restrict__ out)
{
    __shared__ unsigned short tS[TI * LN];            // 32 KiB; 16B-slot XOR swizzle by row
    const int tid    = threadIdx.x;
    const int wv     = __builtin_amdgcn_readfirstlane(tid >> 6);   // wave id 0..3
    const int lane   = tid & 63;
    const int i_base = blockIdx.x * TI;
    char* tB = (char*)tS;

    // ---------------- stage 1: 4 rows per wave ----------------
    for (int it = 0; it < 4; ++it) {
        const int row = wv * 4 + it;                  // uniform
        const int i   = i_base + row;
        const int*   nl = nlist + (size_t)i * KNB;
        const float* ep = edges + (size_t)i * (KNB * E);

        unsigned g[KNB];                              // 32 VGPRs, all live across fence
        if (NB) {
            #pragma unroll
            for (int j = 0; j < KNB; ++j) {
                unsigned idx = (unsigned)nl[j];       // wave-uniform -> s_load
                if (idx >= (unsigned)NN) idx = 0u;
                g[j] = ((const unsigned*)(nodesBf + (size_t)idx * F))[lane];  // 4B/lane
            }
        } else {
            #pragma unroll
            for (int j = 0; j < KNB; ++j) {
                unsigned idx = (unsigned)nl[j];
                if (idx >= (unsigned)NN) idx = 0u;
                const float2 fv = ((const float2*)(nodes + (size_t)idx * F))[lane];
                g[j] = ((unsigned)f2bf(fv.y) << 16) | (unsigned)f2bf(fv.x);
            }
        }
        __builtin_amdgcn_sched_barrier(0);            // loads may NOT sink below this

        float a0[E], a1[E];
        #pragma unroll
        for (int n = 0; n < E; ++n) { a0[n] = 0.f; a1[n] = 0.f; }
        #pragma unroll
        for (int j = 0; j < KNB; ++j) {               // consume in issue order
            const float v0 = bf2f((unsigned short)(g[j] & 0xffff));
            const float v1 = bf2f((unsigned short)(g[j] >> 16));
            const float4 e0 = *(const float4*)(ep + j * 8);      // uniform -> s_load
            const float4 e1 = *(const float4*)(ep + j * 8 + 4);
            a0[0] = __builtin_fmaf(e0.x, v0, a0[0]); a1[0] = __builtin_fmaf(e0.x, v1, a1[0]);
            a0[1] = __builtin_fmaf(e0.y, v0, a0[1]); a1[1] = __builtin_fmaf(e0.y, v1, a1[1]);
            a0[2] = __builtin_fmaf(e0.z, v0, a0[2]); a1[2] = __builtin_fmaf(e0.z, v1, a1[2]);
            a0[3] = __builtin_fmaf(e0.w, v0, a0[3]); a1[3] = __builtin_fmaf(e0.w, v1, a1[3]);
            a0[4] = __builtin_fmaf(e1.x, v0, a0[4]); a1[4] = __builtin_fmaf(e1.x, v1, a1[4]);
            a0[5] = __builtin_fmaf(e1.y, v0, a0[5]); a1[5] = __builtin_fmaf(e1.y, v1, a1[5]);
            a0[6] = __builtin_fmaf(e1.z, v0, a0[6]); a1[6] = __builtin_fmaf(e1.z, v1, a1[6]);
            a0[7] = __builtin_fmaf(e1.w, v0, a0[7]); a1[7] = __builtin_fmaf(e1.w, v1, a1[7]);
        }

        // pack 16 bf16 (ln = lane*16 + 0..15 of row), swizzled 16B-slot store.
        // pk0 -> slot 2*lane, pk1 -> slot 2*lane+1; write order swapped by p2 so
        // each ds_write_b128 covers all 8 bank groups.
        uint4 pk0, pk1;
        pk0.x = (unsigned)f2bf(a0[0]) | ((unsigned)f2bf(a0[1]) << 16);
        pk0.y = (unsigned)f2bf(a0[2]) | ((unsigned)f2bf(a0[3]) << 16);
        pk0.z = (unsigned)f2bf(a0[4]) | ((unsigned)f2bf(a0[5]) << 16);
        pk0.w = (unsigned)f2bf(a0[6]) | ((unsigned)f2bf(a0[7]) << 16);
        pk1.x = (unsigned)f2bf(a1[0]) | ((unsigned)f2bf(a1[1]) << 16);
        pk1.y = (unsigned)f2bf(a1[2]) | ((unsigned)f2bf(a1[3]) << 16);
        pk1.z = (unsigned)f2bf(a1[4]) | ((unsigned)f2bf(a1[5]) << 16);
        pk1.w = (unsigned)f2bf(a1[6]) | ((unsigned)f2bf(a1[7]) << 16);
        const int p2 = (lane >> 2) & 1;
        const int s  = (row & 7) << 4;
        const int rb = row * (LN * 2);
        const uint4 first  = p2 ? pk1 : pk0;
        const uint4 second = p2 ? pk0 : pk1;
        *(uint4*)(tB + rb + ((lane * 32 + (p2 << 4))      ^ s)) = first;
        *(uint4*)(tB + rb + ((lane * 32 + 16 - (p2 << 4)) ^ s)) = second;
    }
    __syncthreads();

    // ---------------- stage 2: MFMA ----------------
    const int colm = lane & 15;                       // i-row for A, m-col for B/C
    const int kq   = lane >> 4;
    const int mt0  = wv * 2, mt1 = wv * 2 + 1;

    f32x4 c0 = {0.f, 0.f, 0.f, 0.f};
    f32x4 c1 = {0.f, 0.f, 0.f, 0.f};

    const int arow = colm * (LN * 2);
    const int asw  = (colm & 7) << 4;

    #pragma unroll 4
    for (int kb = 0; kb < LN / 32; ++kb) {
        union { short8v v; uint2 u[2]; } af;
        af.u[0] = *(const uint2*)(tB + arow + ((kb * 64      + kq * 8) ^ asw)); // k=kb*32+kq*4+e
        af.u[1] = *(const uint2*)(tB + arow + ((kb * 64 + 32 + kq * 8) ^ asw)); // k=kb*32+16+kq*4+e
        union { short8v v; uint4 u; } b0, b1;
        b0.u = *(const uint4*)(w2f + ((size_t)((kb * 128 + mt0 * 16 + colm) * 4 + kq)) * 8);
        b1.u = *(const uint4*)(w2f + ((size_t)((kb * 128 + mt1 * 16 + colm) * 4 + kq)) * 8);
        c0 = __builtin_amdgcn_mfma_f32_16x16x32_bf16(af.v, b0.v, c0, 0, 0, 0);
        c1 = __builtin_amdgcn_mfma_f32_16x16x32_bf16(af.v, b1.v, c1, 0, 0, 0);
    }

    // C/D: col = lane&15, row = (lane>>4)*4 + r   [measured m89]
    #pragma unroll
    for (int r = 0; r < 4; ++r) {
        const int ii = kq * 4 + r;
        const int gi = i_base + ii;
        const float sc = inv_degree[gi];
        out[(size_t)gi * F + mt0 * 16 + colm] = sc * c0[r];
        out[(size_t)gi * F + mt1 * 16 + colm] = sc * c1[r];
    }
}

// ---------- fallback (round-1 kernel, pure fp32) for tiny ws ----------
__global__ __launch_bounds__(256, 2)
void mp_fused_fallback(const float* __restrict__ nodes, const int* __restrict__ nlist,
                       const float* __restrict__ edges, const float* __restrict__ inv_degree,
                       const float* __restrict__ w, float* __restrict__ out)
{
    __shared__ float tLds[TI * F * E];
    const int tid = threadIdx.x;
    const int i_base = blockIdx.x * TI;
    {
        const int l = tid & (F - 1);
        const int half = __builtin_amdgcn_readfirstlane(tid >> 7);
        for (int g = 0; g < TI / 2; ++g) {
            const int ii = g * 2 + half;
            const int i = i_base + ii;
            float acc[E];
            #pragma unroll
            for (int n = 0; n < E; ++n) acc[n] = 0.f;
            const int* nl = nlist + i * KNB;
            const float* ep = edges + (size_t)i * (KNB * E);
            #pragma unroll 4
            for (int j = 0; j < KNB; ++j) {
                unsigned idx = (unsigned)nl[j];
                if (idx >= (unsigned)NN) idx = 0u;
                const float v = nodes[idx * F + l];
                #pragma unroll
                for (int n = 0; n < E; ++n) acc[n] = __builtin_fmaf(ep[j * E + n], v, acc[n]);
            }
            float4* dst = (float4*)&tLds[ii * (F * E) + l * E];
            dst[0] = make_float4(acc[0], acc[1], acc[2], acc[3]);
            dst[1] = make_float4(acc[4], acc[5], acc[6], acc[7]);
        }
    }
    __syncthreads();
    const int m_lo = tid & 63;
    const int q = __builtin_amdgcn_readfirstlane(tid >> 6);
    float accA[TI], accB[TI];
    #pragma unroll
    for (int ii = 0; ii < TI; ++ii) { accA[ii] = 0.f; accB[ii] = 0.f; }
    for (int lq = 0; lq < F / 4; ++lq) {
        const int l = q * (F / 4) + lq;
        const float4* wp0 = (const float4*)&w[(size_t)l * (F * E) + (size_t)m_lo * E];
        const float4* wp1 = (const float4*)&w[(size_t)l * (F * E) + (size_t)(m_lo + 64) * E];
        const float4 w0a = wp0[0], w0b = wp0[1];
        const float4 w1a = wp1[0], w1b = wp1[1];
        #pragma unroll
        for (int ii = 0; ii < TI; ++ii) {
            const float4* tp = (const float4*)&tLds[ii * (F * E) + l * E];
            const float4 ta = tp[0], tb = tp[1];
            float sA = accA[ii], sB = accB[ii];
            sA = __builtin_fmaf(ta.x, w0a.x, sA); sA = __builtin_fmaf(ta.y, w0a.y, sA);
            sA = __builtin_fmaf(ta.z, w0a.z, sA); sA = __builtin_fmaf(ta.w, w0a.w, sA);
            sA = __builtin_fmaf(tb.x, w0b.x, sA); sA = __builtin_fmaf(tb.y, w0b.y, sA);
            sA = __builtin_fmaf(tb.z, w0b.z, sA); sA = __builtin_fmaf(tb.w, w0b.w, sA);
            sB = __builtin_fmaf(ta.x, w1a.x, sB); sB = __builtin_fmaf(ta.y, w1a.y, sB);
            sB = __builtin_fmaf(ta.z, w1a.z, sB); sB = __builtin_fmaf(ta.w, w1a.w, sB);
            sB = __builtin_fmaf(tb.x, w1b.x, sB); sB = __builtin_fmaf(tb.y, w1b.y, sB);
            sB = __builtin_fmaf(tb.z, w1b.z, sB); sB = __builtin_fmaf(tb.w, w1b.w, sB);
            accA[ii] = sA; accB[ii] = sB;
        }
    }
    __syncthreads();
    float* pLds = tLds;
    #pragma unroll
    for (int ii = 0; ii < TI; ++ii) {
        pLds[q * (TI * F) + ii * F + m_lo] = accA[ii];
        pLds[q * (TI * F) + ii * F + m_lo + 64] = accB[ii];
    }
    __syncthreads();
    #pragma unroll
    for (int r = 0; r < (TI * F) / 256; ++r) {
        const int o = r * 256 + tid;
        const int ii = o >> 7;
        const int m = o & (F - 1);
        const float s = pLds[0 * (TI * F) + ii * F + m] + pLds[1 * (TI * F) + ii * F + m]
                      + pLds[2 * (TI * F) + ii * F + m] + pLds[3 * (TI * F) + ii * F + m];
        const int i = i_base + ii;
        out[(size_t)i * F + m] = inv_degree[i] * s;
    }
}

extern "C" void kernel_launch(void* const* d_in, const int* in_sizes, int n_in,
                              void* d_out, int out_size, void* d_ws, size_t ws_size,
                              hipStream_t stream) {
    const float* nodes      = (const float*)d_in[0];
    const int*   nlist      = (const int*)d_in[1];
    const float* edges      = (const float*)d_in[2];
    const float* inv_degree = (const float*)d_in[3];
    const float* w          = (const float*)d_in[4];
    float* out = (float*)d_out;
    (void)in_sizes; (void)n_in; (void)out_size;

    const size_t need_w2 = (size_t)LN * F * 2;                  // 256 KiB
    const size_t need_nb = (size_t)NN * F * 2;                  // 12.8 MiB

    if (ws_size < need_w2) {
        mp_fused_fallback<<<dim3(NN / TI), dim3(256), 0, stream>>>(
            nodes, nlist, edges, inv_degree, w, out);
        return;
    }
    unsigned short* w2f = (unsigned short*)d_ws;
    unsigned short* nb  = (unsigned short*)((char*)d_ws + need_w2);

    prep_w_kernel<<<dim3((LN * F) / 256), dim3(256), 0, stream>>>(w, w2f);
    if (ws_size >= need_w2 + need_nb) {
        prep_nodes_kernel<<<dim3(NN * F / 8 / 256), dim3(256), 0, stream>>>(nodes, nb);
        mp_main_kernel<true><<<dim3(NN / TI), dim3(256), 0, stream>>>(
            nodes, nb, nlist, edges, inv_degree, w2f, out);
    } else {
        mp_main_kernel<false><<<dim3(NN / TI), dim3(256), 0, stream>>>(
            nodes, nb, nlist, edges, inv_degree, w2f, out);
    }
}

// Round 7
// 98.796 us; speedup vs baseline: 1.9375x; 1.2147x over previous
//
#include <hip/hip_runtime.h>
#include <hip/hip_bf16.h>

static constexpr int NN  = 50000;  // nodes
static constexpr int KNB = 32;     // neighbors
static constexpr int F   = 128;    // features
static constexpr int E   = 8;      // edge features
static constexpr int TI  = 16;     // nodes per block (3125 blocks)
static constexpr int LN  = F * E;  // 1024 contraction length

typedef __attribute__((ext_vector_type(8))) short short8v;
typedef __attribute__((ext_vector_type(4))) float f32x4;

__device__ __forceinline__ unsigned short f2bf(float x) {
    unsigned u = __float_as_uint(x);
    unsigned r = (u + 0x7fff + ((u >> 16) & 1)) >> 16;   // RNE
    return (unsigned short)r;
}
__device__ __forceinline__ float bf2f(unsigned short b) {
    return __uint_as_float(((unsigned)b) << 16);
}

// ---------- prep A: w[l,m,n] -> W2f bf16 in B-fragment order ----------
// W2f[((kb*128 + m)*4 + kq)*8 + e8] = bf16( w[l,m,n] ) where
//   k = kb*32 + kq*4 + (e8&3) + (e8>>2)*16 ,  l = k>>3, n = k&7
__global__ void prep_w_kernel(const float* __restrict__ w, unsigned short* __restrict__ w2f) {
    int o  = blockIdx.x * 256 + threadIdx.x;          // 131072 total
    int e8 = o & 7, kq = (o >> 3) & 3, m = (o >> 5) & 127, kb = o >> 12;
    int k  = kb * 32 + kq * 4 + (e8 & 3) + ((e8 >> 2) << 4);
    int l  = k >> 3, n = k & 7;
    w2f[o] = f2bf(w[(size_t)(l * F + m) * E + n]);
}

// ---------- prep B: nodes fp32 -> bf16 (3125 blocks x 256 thr x 8 elems = exact) ----------
__global__ void prep_nodes_kernel(const float* __restrict__ nodes, unsigned short* __restrict__ nb) {
    int t = blockIdx.x * 256 + threadIdx.x;
    const float4* s = (const float4*)nodes + (size_t)t * 2;
    float4 a = s[0], b = s[1];
    uint4 pk;
    pk.x = (unsigned)f2bf(a.x) | ((unsigned)f2bf(a.y) << 16);
    pk.y = (unsigned)f2bf(a.z) | ((unsigned)f2bf(a.w) << 16);
    pk.z = (unsigned)f2bf(b.x) | ((unsigned)f2bf(b.y) << 16);
    pk.w = (unsigned)f2bf(b.z) | ((unsigned)f2bf(b.w) << 16);
    ((uint4*)nb)[t] = pk;
}

// ---------- main fused kernel ----------
// 512 threads (8 waves) per block, TI=16 nodes, 32 KiB LDS -> 4 blocks/CU =
// 32 waves/CU = 100% occupancy. Stage-1 latency hiding comes from TLP.
// stage 1: wave wv computes rows {2wv, 2wv+1}: T[row][ln] = sum_j e[i,j,n]*nodes[nl[i,j],l]
// stage 2: wave wv computes C m-tile mt=wv: out[i][m] = inv[i]*sum_ln T*W2
template<bool NB>
__global__ __launch_bounds__(512, 8)
void mp_main_kernel(const float* __restrict__ nodes,
                    const unsigned short* __restrict__ nodesBf,
                    const int*   __restrict__ nlist,
                    const float* __restrict__ edges,
                    const float* __restrict__ inv_degree,
                    const unsigned short* __restrict__ w2f,
                    float* __restrict__ out)
{
    __shared__ unsigned short tS[TI * LN];            // 32 KiB; 16B-slot XOR swizzle by row
    const int tid    = threadIdx.x;
    const int wv     = __builtin_amdgcn_readfirstlane(tid >> 6);   // wave id 0..7
    const int lane   = tid & 63;
    const int i_base = blockIdx.x * TI;
    char* tB = (char*)tS;

    // ---------------- stage 1: 2 rows per wave ----------------
    for (int it = 0; it < 2; ++it) {
        const int row = wv * 2 + it;                  // uniform 0..15
        const int i   = i_base + row;
        const int*   nl = nlist + (size_t)i * KNB;
        const float* ep = edges + (size_t)i * (KNB * E);

        unsigned g[KNB];
        if (NB) {
            #pragma unroll
            for (int j = 0; j < KNB; ++j) {
                unsigned idx = (unsigned)nl[j];       // wave-uniform -> s_load
                if (idx >= (unsigned)NN) idx = 0u;
                g[j] = ((const unsigned*)(nodesBf + (size_t)idx * F))[lane];  // 4B/lane
            }
        } else {
            #pragma unroll
            for (int j = 0; j < KNB; ++j) {
                unsigned idx = (unsigned)nl[j];
                if (idx >= (unsigned)NN) idx = 0u;
                const float2 fv = ((const float2*)(nodes + (size_t)idx * F))[lane];
                g[j] = ((unsigned)f2bf(fv.y) << 16) | (unsigned)f2bf(fv.x);
            }
        }
        __builtin_amdgcn_sched_barrier(0);

        float a0[E], a1[E];
        #pragma unroll
        for (int n = 0; n < E; ++n) { a0[n] = 0.f; a1[n] = 0.f; }
        #pragma unroll
        for (int j = 0; j < KNB; ++j) {
            const float v0 = bf2f((unsigned short)(g[j] & 0xffff));
            const float v1 = bf2f((unsigned short)(g[j] >> 16));
            const float4 e0 = *(const float4*)(ep + j * 8);      // uniform -> s_load
            const float4 e1 = *(const float4*)(ep + j * 8 + 4);
            a0[0] = __builtin_fmaf(e0.x, v0, a0[0]); a1[0] = __builtin_fmaf(e0.x, v1, a1[0]);
            a0[1] = __builtin_fmaf(e0.y, v0, a0[1]); a1[1] = __builtin_fmaf(e0.y, v1, a1[1]);
            a0[2] = __builtin_fmaf(e0.z, v0, a0[2]); a1[2] = __builtin_fmaf(e0.z, v1, a1[2]);
            a0[3] = __builtin_fmaf(e0.w, v0, a0[3]); a1[3] = __builtin_fmaf(e0.w, v1, a1[3]);
            a0[4] = __builtin_fmaf(e1.x, v0, a0[4]); a1[4] = __builtin_fmaf(e1.x, v1, a1[4]);
            a0[5] = __builtin_fmaf(e1.y, v0, a0[5]); a1[5] = __builtin_fmaf(e1.y, v1, a1[5]);
            a0[6] = __builtin_fmaf(e1.z, v0, a0[6]); a1[6] = __builtin_fmaf(e1.z, v1, a1[6]);
            a0[7] = __builtin_fmaf(e1.w, v0, a0[7]); a1[7] = __builtin_fmaf(e1.w, v1, a1[7]);
        }

        // pack 16 bf16 (ln = lane*16 + 0..15 of row), swizzled 16B-slot store.
        uint4 pk0, pk1;
        pk0.x = (unsigned)f2bf(a0[0]) | ((unsigned)f2bf(a0[1]) << 16);
        pk0.y = (unsigned)f2bf(a0[2]) | ((unsigned)f2bf(a0[3]) << 16);
        pk0.z = (unsigned)f2bf(a0[4]) | ((unsigned)f2bf(a0[5]) << 16);
        pk0.w = (unsigned)f2bf(a0[6]) | ((unsigned)f2bf(a0[7]) << 16);
        pk1.x = (unsigned)f2bf(a1[0]) | ((unsigned)f2bf(a1[1]) << 16);
        pk1.y = (unsigned)f2bf(a1[2]) | ((unsigned)f2bf(a1[3]) << 16);
        pk1.z = (unsigned)f2bf(a1[4]) | ((unsigned)f2bf(a1[5]) << 16);
        pk1.w = (unsigned)f2bf(a1[6]) | ((unsigned)f2bf(a1[7]) << 16);
        const int p2 = (lane >> 2) & 1;
        const int s  = (row & 7) << 4;
        const int rb = row * (LN * 2);
        const uint4 first  = p2 ? pk1 : pk0;
        const uint4 second = p2 ? pk0 : pk1;
        *(uint4*)(tB + rb + ((lane * 32 + (p2 << 4))      ^ s)) = first;
        *(uint4*)(tB + rb + ((lane * 32 + 16 - (p2 << 4)) ^ s)) = second;
    }
    __syncthreads();

    // ---------------- stage 2: MFMA, one 16x16 m-tile per wave ----------------
    const int colm = lane & 15;                       // i-row for A, m-col for B/C
    const int kq   = lane >> 4;
    const int mt   = wv;                              // m-tile 0..7

    f32x4 c0 = {0.f, 0.f, 0.f, 0.f};

    const int arow = colm * (LN * 2);
    const int asw  = (colm & 7) << 4;

    #pragma unroll 4
    for (int kb = 0; kb < LN / 32; ++kb) {
        union { short8v v; uint2 u[2]; } af;
        af.u[0] = *(const uint2*)(tB + arow + ((kb * 64      + kq * 8) ^ asw)); // k=kb*32+kq*4+e
        af.u[1] = *(const uint2*)(tB + arow + ((kb * 64 + 32 + kq * 8) ^ asw)); // k=kb*32+16+kq*4+e
        union { short8v v; uint4 u; } b0;
        b0.u = *(const uint4*)(w2f + ((size_t)((kb * 128 + mt * 16 + colm) * 4 + kq)) * 8);
        c0 = __builtin_amdgcn_mfma_f32_16x16x32_bf16(af.v, b0.v, c0, 0, 0, 0);
    }

    // C/D: col = lane&15, row = (lane>>4)*4 + r   [measured m89]
    #pragma unroll
    for (int r = 0; r < 4; ++r) {
        const int ii = kq * 4 + r;
        const int gi = i_base + ii;
        out[(size_t)gi * F + mt * 16 + colm] = inv_degree[gi] * c0[r];
    }
}

// ---------- fallback (round-1 kernel, pure fp32) for tiny ws ----------
__global__ __launch_bounds__(256, 2)
void mp_fused_fallback(const float* __restrict__ nodes, const int* __restrict__ nlist,
                       const float* __restrict__ edges, const float* __restrict__ inv_degree,
                       const float* __restrict__ w, float* __restrict__ out)
{
    __shared__ float tLds[TI * F * E];
    const int tid = threadIdx.x;
    const int i_base = blockIdx.x * TI;
    {
        const int l = tid & (F - 1);
        const int half = __builtin_amdgcn_readfirstlane(tid >> 7);
        for (int g = 0; g < TI / 2; ++g) {
            const int ii = g * 2 + half;
            const int i = i_base + ii;
            float acc[E];
            #pragma unroll
            for (int n = 0; n < E; ++n) acc[n] = 0.f;
            const int* nl = nlist + i * KNB;
            const float* ep = edges + (size_t)i * (KNB * E);
            #pragma unroll 4
            for (int j = 0; j < KNB; ++j) {
                unsigned idx = (unsigned)nl[j];
                if (idx >= (unsigned)NN) idx = 0u;
                const float v = nodes[idx * F + l];
                #pragma unroll
                for (int n = 0; n < E; ++n) acc[n] = __builtin_fmaf(ep[j * E + n], v, acc[n]);
            }
            float4* dst = (float4*)&tLds[ii * (F * E) + l * E];
            dst[0] = make_float4(acc[0], acc[1], acc[2], acc[3]);
            dst[1] = make_float4(acc[4], acc[5], acc[6], acc[7]);
        }
    }
    __syncthreads();
    const int m_lo = tid & 63;
    const int q = __builtin_amdgcn_readfirstlane(tid >> 6);
    float accA[TI], accB[TI];
    #pragma unroll
    for (int ii = 0; ii < TI; ++ii) { accA[ii] = 0.f; accB[ii] = 0.f; }
    for (int lq = 0; lq < F / 4; ++lq) {
        const int l = q * (F / 4) + lq;
        const float4* wp0 = (const float4*)&w[(size_t)l * (F * E) + (size_t)m_lo * E];
        const float4* wp1 = (const float4*)&w[(size_t)l * (F * E) + (size_t)(m_lo + 64) * E];
        const float4 w0a = wp0[0], w0b = wp0[1];
        const float4 w1a = wp1[0], w1b = wp1[1];
        #pragma unroll
        for (int ii = 0; ii < TI; ++ii) {
            const float4* tp = (const float4*)&tLds[ii * (F * E) + l * E];
            const float4 ta = tp[0], tb = tp[1];
            float sA = accA[ii], sB = accB[ii];
            sA = __builtin_fmaf(ta.x, w0a.x, sA); sA = __builtin_fmaf(ta.y, w0a.y, sA);
            sA = __builtin_fmaf(ta.z, w0a.z, sA); sA = __builtin_fmaf(ta.w, w0a.w, sA);
            sA = __builtin_fmaf(tb.x, w0b.x, sA); sA = __builtin_fmaf(tb.y, w0b.y, sA);
            sA = __builtin_fmaf(tb.z, w0b.z, sA); sA = __builtin_fmaf(tb.w, w0b.w, sA);
            sB = __builtin_fmaf(ta.x, w1a.x, sB); sB = __builtin_fmaf(ta.y, w1a.y, sB);
            sB = __builtin_fmaf(ta.z, w1a.z, sB); sB = __builtin_fmaf(ta.w, w1a.w, sB);
            sB = __builtin_fmaf(tb.x, w1b.x, sB); sB = __builtin_fmaf(tb.y, w1b.y, sB);
            sB = __builtin_fmaf(tb.z, w1b.z, sB); sB = __builtin_fmaf(tb.w, w1b.w, sB);
            accA[ii] = sA; accB[ii] = sB;
        }
    }
    __syncthreads();
    float* pLds = tLds;
    #pragma unroll
    for (int ii = 0; ii < TI; ++ii) {
        pLds[q * (TI * F) + ii * F + m_lo] = accA[ii];
        pLds[q * (TI * F) + ii * F + m_lo + 64] = accB[ii];
    }
    __syncthreads();
    #pragma unroll
    for (int r = 0; r < (TI * F) / 256; ++r) {
        const int o = r * 256 + tid;
        const int ii = o >> 7;
        const int m = o & (F - 1);
        const float s = pLds[0 * (TI * F) + ii * F + m] + pLds[1 * (TI * F) + ii * F + m]
                      + pLds[2 * (TI * F) + ii * F + m] + pLds[3 * (TI * F) + ii * F + m];
        const int i = i_base + ii;
        out[(size_t)i * F + m] = inv_degree[i] * s;
    }
}

extern "C" void kernel_launch(void* const* d_in, const int* in_sizes, int n_in,
                              void* d_out, int out_size, void* d_ws, size_t ws_size,
                              hipStream_t stream) {
    const float* nodes      = (const float*)d_in[0];
    const int*   nlist      = (const int*)d_in[1];
    const float* edges      = (const float*)d_in[2];
    const float* inv_degree = (const float*)d_in[3];
    const float* w          = (const float*)d_in[4];
    float* out = (float*)d_out;
    (void)in_sizes; (void)n_in; (void)out_size;

    const size_t need_w2 = (size_t)LN * F * 2;                  // 256 KiB
    const size_t need_nb = (size_t)NN * F * 2;                  // 12.8 MiB

    if (ws_size < need_w2) {
        mp_fused_fallback<<<dim3(NN / TI), dim3(256), 0, stream>>>(
            nodes, nlist, edges, inv_degree, w, out);
        return;
    }
    unsigned short* w2f = (unsigned short*)d_ws;
    unsigned short* nb  = (unsigned short*)((char*)d_ws + need_w2);

    prep_w_kernel<<<dim3((LN * F) / 256), dim3(256), 0, stream>>>(w, w2f);
    if (ws_size >= need_w2 + need_nb) {
        prep_nodes_kernel<<<dim3(NN * F / 8 / 256), dim3(256), 0, stream>>>(nodes, nb);
        mp_main_kernel<true><<<dim3(NN / TI), dim3(512), 0, stream>>>(
            nodes, nb, nlist, edges, inv_degree, w2f, out);
    } else {
        mp_main_kernel<false><<<dim3(NN / TI), dim3(512), 0, stream>>>(
            nodes, nb, nlist, edges, inv_degree, w2f, out);
    }
}